// Round 3
// baseline (477.108 us; speedup 1.0000x reference)
//
#include <hip/hip_runtime.h>

// ---------------------------------------------------------------------------
// GCN 3-layer forward: N=50000, E=600000, dims 128 -> 128 -> 64 -> 16.
// CSR (packed int2 {src, w}) built once per call, reused by all layers.
// GEMM: register-resident A (broadcast global loads, no staging barrier),
//       W LDS-staged in <=32KB chunks. RT rows x 4 cols per thread.
// AGG:  TPN = F/4 lanes per node, float4 gathers, 4-edge unroll.
// ---------------------------------------------------------------------------

__device__ inline void fmaw(float4& acc, float a, const float4& w) {
  acc.x = fmaf(a, w.x, acc.x);
  acc.y = fmaf(a, w.y, acc.y);
  acc.z = fmaf(a, w.z, acc.z);
  acc.w = fmaf(a, w.w, acc.w);
}

__device__ inline void fma4(float4& acc, const float4& g, float w) {
  acc.x = fmaf(g.x, w, acc.x);
  acc.y = fmaf(g.y, w, acc.y);
  acc.z = fmaf(g.z, w, acc.z);
  acc.w = fmaf(g.w, w, acc.w);
}

// ------------------------------- CSR build ---------------------------------

__global__ void count_kernel(const int* __restrict__ dst, int* __restrict__ cnt, int E) {
  int e = blockIdx.x * blockDim.x + threadIdx.x;
  if (e < E) atomicAdd(&cnt[dst[e]], 1);
}

// block-scan of counts + 1 atomic/block -> CSR slot ranges; also emits dinv.
__global__ void alloc_kernel(const int* __restrict__ cnt, int* __restrict__ row_start,
                             int* __restrict__ cursor, int* __restrict__ counter,
                             float* __restrict__ dinv, int n) {
  __shared__ int sbuf[256];
  __shared__ int sbase;
  int t = threadIdx.x;
  int node = blockIdx.x * 256 + t;
  int c = (node < n) ? cnt[node] : 0;
  if (node < n) dinv[node] = rsqrtf((float)c + 1.0f);
  sbuf[t] = c;
  __syncthreads();
#pragma unroll
  for (int offs = 1; offs < 256; offs <<= 1) {
    int v = sbuf[t];
    int add = (t >= offs) ? sbuf[t - offs] : 0;
    __syncthreads();
    sbuf[t] = v + add;
    __syncthreads();
  }
  if (t == 255) sbase = atomicAdd(counter, sbuf[255]);
  __syncthreads();
  if (node < n) {
    int excl = sbuf[t] - c;
    row_start[node] = sbase + excl;
    cursor[node] = sbase + excl;
  }
}

__global__ void scatter_kernel(const int* __restrict__ src, const int* __restrict__ dst,
                               const float* __restrict__ dinv, int* __restrict__ cursor,
                               int2* __restrict__ csr, int E) {
  int e = blockIdx.x * blockDim.x + threadIdx.x;
  if (e < E) {
    int s = src[e];
    int d = dst[e];
    int pos = atomicAdd(&cursor[d], 1);
    int2 pk;
    pk.x = s;
    pk.y = __float_as_int(dinv[s] * dinv[d]);
    csr[pos] = pk;
  }
}

// --------------------------------- GEMM ------------------------------------
// C[n x F] = A[n x K] @ W[K x F].
// Thread (tx, ty) owns rows row0..row0+RT-1, cols tx*4..tx*4+3.
// A read: all CG lanes sharing a row load the SAME address (HW broadcast,
// L1-resident) sequentially down K -> no scatter, no barrier on A path.
// W chunk (KC x F, <=32KB) staged in LDS; 2-way-broadcast ds_read_b128.
template <int K, int F, int RT, int KC>
__global__ __launch_bounds__(256) void gemm_rr(const float* __restrict__ A,
                                               const float* __restrict__ W,
                                               float* __restrict__ C, int n) {
  constexpr int CG = F / 4;       // threads across F
  constexpr int TYG = 256 / CG;   // thread row-groups
  constexpr int RPB = TYG * RT;   // rows per block

  __shared__ float Ws[KC * F];

  int t = threadIdx.x;
  int tx = t % CG;
  int ty = t / CG;
  int row0 = blockIdx.x * RPB + ty * RT;

  // clamped row addresses (loads always in-bounds; stores guarded)
  const float* ap[RT];
#pragma unroll
  for (int r = 0; r < RT; ++r) {
    int rr = row0 + r;
    ap[r] = A + (size_t)(rr < n ? rr : n - 1) * K;
  }

  float4 acc[RT];
#pragma unroll
  for (int r = 0; r < RT; ++r) acc[r] = make_float4(0.f, 0.f, 0.f, 0.f);

  for (int kc = 0; kc < K; kc += KC) {
    __syncthreads();  // protect Ws re-fill (no-op cost on first iter)
    {
      const float4* wg = (const float4*)(W + (size_t)kc * F);
      float4* ws4 = (float4*)Ws;
      for (int i = t; i < KC * F / 4; i += 256) ws4[i] = wg[i];
    }
    __syncthreads();

#pragma unroll
    for (int k4 = 0; k4 < KC / 4; ++k4) {
      float4 a[RT];
#pragma unroll
      for (int r = 0; r < RT; ++r) a[r] = *(const float4*)(ap[r] + kc + k4 * 4);
      float4 w0 = *(const float4*)&Ws[(k4 * 4 + 0) * F + tx * 4];
      float4 w1 = *(const float4*)&Ws[(k4 * 4 + 1) * F + tx * 4];
      float4 w2 = *(const float4*)&Ws[(k4 * 4 + 2) * F + tx * 4];
      float4 w3 = *(const float4*)&Ws[(k4 * 4 + 3) * F + tx * 4];
#pragma unroll
      for (int r = 0; r < RT; ++r) {
        fmaw(acc[r], a[r].x, w0);
        fmaw(acc[r], a[r].y, w1);
        fmaw(acc[r], a[r].z, w2);
        fmaw(acc[r], a[r].w, w3);
      }
    }
  }

#pragma unroll
  for (int r = 0; r < RT; ++r) {
    int rr = row0 + r;
    if (rr < n) *(float4*)&C[(size_t)rr * F + tx * 4] = acc[r];
  }
}

// ------------------------------ Aggregation --------------------------------
// out[i] = sum_e w_e * h[src_e] + dinv[i]^2 * h[i] + bias   (+ReLU)
template <int F, bool RELU>
__global__ __launch_bounds__(256) void agg_kernel(
    const float* __restrict__ h, const int* __restrict__ row_start,
    const int* __restrict__ cnt, const int2* __restrict__ csr,
    const float* __restrict__ dinv, const float* __restrict__ bias,
    float* __restrict__ out, int n) {
  constexpr int TPN = F / 4;      // lanes per node
  constexpr int NPB = 256 / TPN;  // nodes per block
  int node = blockIdx.x * NPB + threadIdx.x / TPN;
  int lane = threadIdx.x % TPN;
  if (node >= n) return;

  float di = dinv[node];
  float sc = di * di;
  float4 hs = *(const float4*)&h[(size_t)node * F + lane * 4];
  float4 acc = make_float4(hs.x * sc, hs.y * sc, hs.z * sc, hs.w * sc);

  int s = row_start[node];
  int e = s + cnt[node];
  int j = s;
  for (; j + 4 <= e; j += 4) {
    int2 p0 = csr[j];
    int2 p1 = csr[j + 1];
    int2 p2 = csr[j + 2];
    int2 p3 = csr[j + 3];
    float4 g0 = *(const float4*)&h[(size_t)p0.x * F + lane * 4];
    float4 g1 = *(const float4*)&h[(size_t)p1.x * F + lane * 4];
    float4 g2 = *(const float4*)&h[(size_t)p2.x * F + lane * 4];
    float4 g3 = *(const float4*)&h[(size_t)p3.x * F + lane * 4];
    fma4(acc, g0, __int_as_float(p0.y));
    fma4(acc, g1, __int_as_float(p1.y));
    fma4(acc, g2, __int_as_float(p2.y));
    fma4(acc, g3, __int_as_float(p3.y));
  }
  for (; j < e; ++j) {
    int2 p = csr[j];
    float4 g = *(const float4*)&h[(size_t)p.x * F + lane * 4];
    fma4(acc, g, __int_as_float(p.y));
  }

  float4 b4 = *(const float4*)&bias[lane * 4];
  float4 r = make_float4(acc.x + b4.x, acc.y + b4.y, acc.z + b4.z, acc.w + b4.w);
  if (RELU) {
    r.x = fmaxf(r.x, 0.f);
    r.y = fmaxf(r.y, 0.f);
    r.z = fmaxf(r.z, 0.f);
    r.w = fmaxf(r.w, 0.f);
  }
  *(float4*)&out[(size_t)node * F + lane * 4] = r;
}

// -------------------------------- launch -----------------------------------

extern "C" void kernel_launch(void* const* d_in, const int* in_sizes, int n_in,
                              void* d_out, int out_size, void* d_ws, size_t ws_size,
                              hipStream_t stream) {
  const float* x = (const float*)d_in[0];
  const int* edge = (const int*)d_in[1];
  const float* W1 = (const float*)d_in[2];
  const float* b1 = (const float*)d_in[3];
  const float* W2 = (const float*)d_in[4];
  const float* b2 = (const float*)d_in[5];
  const float* W3 = (const float*)d_in[6];
  const float* b3 = (const float*)d_in[7];

  const int N = in_sizes[0] / 128;
  const int E = in_sizes[1] / 2;
  const int* src = edge;       // edge_index[0]
  const int* dstp = edge + E;  // edge_index[1]
  float* out = (float*)d_out;

  size_t off = 0;
  auto take = [&](size_t bytes) -> void* {
    void* r = (char*)d_ws + off;
    off += (bytes + 255) & ~(size_t)255;
    return r;
  };
  int* counter = (int*)take(4);
  int* cnt = (int*)take((size_t)N * 4);
  float* dinv = (float*)take((size_t)N * 4);
  int* row_start = (int*)take((size_t)N * 4);
  int* cursor = (int*)take((size_t)N * 4);
  int2* csr = (int2*)take((size_t)E * 8);
  float* bufh = (float*)take((size_t)N * 128 * 4);
  float* bufa = (float*)take((size_t)N * 128 * 4);

  // zero counter + cnt (first two regions, contiguous)
  hipMemsetAsync(d_ws, 0, 256 + (size_t)N * 4, stream);

  const int TB = 256;
  int eg = (E + TB - 1) / TB;
  int ng = (N + TB - 1) / TB;

  count_kernel<<<eg, TB, 0, stream>>>(dstp, cnt, E);
  alloc_kernel<<<ng, TB, 0, stream>>>(cnt, row_start, cursor, counter, dinv, N);
  scatter_kernel<<<eg, TB, 0, stream>>>(src, dstp, dinv, cursor, csr, E);

  // Layer 1: 128 -> 128 (+ReLU).  RT=2, RPB=16, Ws 32KB, grid 3125.
  gemm_rr<128, 128, 2, 64><<<(N + 15) / 16, 256, 0, stream>>>(x, W1, bufh, N);
  agg_kernel<128, true><<<(N + 7) / 8, 256, 0, stream>>>(bufh, row_start, cnt, csr, dinv, b1,
                                                         bufa, N);
  // Layer 2: 128 -> 64 (+ReLU).  RT=2, RPB=32, Ws 32KB, grid 1563.
  gemm_rr<128, 64, 2, 128><<<(N + 31) / 32, 256, 0, stream>>>(bufa, W2, bufh, N);
  agg_kernel<64, true><<<(N + 15) / 16, 256, 0, stream>>>(bufh, row_start, cnt, csr, dinv, b2,
                                                          bufa, N);
  // Layer 3: 64 -> 16.  RT=1, RPB=64, Ws 4KB, grid 782.
  gemm_rr<64, 16, 1, 64><<<(N + 63) / 64, 256, 0, stream>>>(bufa, W3, bufh, N);
  agg_kernel<16, false><<<(N + 63) / 64, 256, 0, stream>>>(bufh, row_start, cnt, csr, dinv, b3,
                                                           out, N);
}

// Round 4
// 315.665 us; speedup vs baseline: 1.5114x; 1.5114x over previous
//
#include <hip/hip_runtime.h>

// ---------------------------------------------------------------------------
// GCN 3-layer forward: N=50000, E=600000, dims 128 -> 128 -> 64 -> 16.
// CSR (packed int2 {src, w}) built once per call, reused by all layers.
// GEMM: tiled, coalesced VGPR staging -> padded LDS, register chunk-prefetch
//       (next chunk's global loads in flight during current chunk's FMAs),
//       float4 LDS reads, RT rows x 4 cols per thread.
// AGG:  TPN = F/4 lanes per node, float4 gathers, 4-edge unroll.
// ---------------------------------------------------------------------------

__device__ inline void fmaw(float4& acc, float a, const float4& w) {
  acc.x = fmaf(a, w.x, acc.x);
  acc.y = fmaf(a, w.y, acc.y);
  acc.z = fmaf(a, w.z, acc.z);
  acc.w = fmaf(a, w.w, acc.w);
}

__device__ inline void fma4(float4& acc, const float4& g, float w) {
  acc.x = fmaf(g.x, w, acc.x);
  acc.y = fmaf(g.y, w, acc.y);
  acc.z = fmaf(g.z, w, acc.z);
  acc.w = fmaf(g.w, w, acc.w);
}

// ------------------------------- CSR build ---------------------------------

__global__ void count_kernel(const int* __restrict__ dst, int* __restrict__ cnt, int E) {
  int e = blockIdx.x * blockDim.x + threadIdx.x;
  if (e < E) atomicAdd(&cnt[dst[e]], 1);
}

// block-scan of counts + 1 atomic/block -> CSR slot ranges; also emits dinv.
__global__ void alloc_kernel(const int* __restrict__ cnt, int* __restrict__ row_start,
                             int* __restrict__ cursor, int* __restrict__ counter,
                             float* __restrict__ dinv, int n) {
  __shared__ int sbuf[256];
  __shared__ int sbase;
  int t = threadIdx.x;
  int node = blockIdx.x * 256 + t;
  int c = (node < n) ? cnt[node] : 0;
  if (node < n) dinv[node] = rsqrtf((float)c + 1.0f);
  sbuf[t] = c;
  __syncthreads();
#pragma unroll
  for (int offs = 1; offs < 256; offs <<= 1) {
    int v = sbuf[t];
    int add = (t >= offs) ? sbuf[t - offs] : 0;
    __syncthreads();
    sbuf[t] = v + add;
    __syncthreads();
  }
  if (t == 255) sbase = atomicAdd(counter, sbuf[255]);
  __syncthreads();
  if (node < n) {
    int excl = sbuf[t] - c;
    row_start[node] = sbase + excl;
    cursor[node] = sbase + excl;
  }
}

__global__ void scatter_kernel(const int* __restrict__ src, const int* __restrict__ dst,
                               const float* __restrict__ dinv, int* __restrict__ cursor,
                               int2* __restrict__ csr, int E) {
  int e = blockIdx.x * blockDim.x + threadIdx.x;
  if (e < E) {
    int s = src[e];
    int d = dst[e];
    int pos = atomicAdd(&cursor[d], 1);
    int2 pk;
    pk.x = s;
    pk.y = __float_as_int(dinv[s] * dinv[d]);
    csr[pos] = pk;
  }
}

// --------------------------------- GEMM ------------------------------------
// C[n x F] = A[n x K] @ W[K x F].  Thread (tx,ty) owns RT rows x 4 cols.
// As padded [BR][BK+4]: A-tile reads are <=2-way bank-aliased (free).
// Staging: idx -> (row=idx/8, kq=idx%8); 8 lanes cover one row's 128B chunk
// (coalesced 1KB per wave-instr).  Chunk c+1 prefetched into registers while
// chunk c computes; stored to LDS after the barrier.
template <int K, int F, int RT>
__global__ __launch_bounds__(256, 2) void gemm_t(const float* __restrict__ A,
                                                 const float* __restrict__ W,
                                                 float* __restrict__ C, int n) {
  constexpr int BK = 32;
  constexpr int CG = F / 4;
  constexpr int TYG = 256 / CG;
  constexpr int BR = TYG * RT;            // 64 for all three layers
  constexpr int AP = BK + 4;
  constexpr int CHUNKS = K / BK;
  constexpr int APT = (BR * BK) / 1024;   // A float4s per thread (=2)
  constexpr int WTOT = BK * F / 4;        // W float4s per chunk
  constexpr int WPT = (WTOT + 255) / 256;

  __shared__ float As[BR * AP];
  __shared__ float Ws[BK * F];

  int t = threadIdx.x;
  int tx = t % CG;
  int ty = t / CG;
  int rb = blockIdx.x * BR;

  float4 aReg[APT];
  float4 wReg[WPT];

  auto loadA = [&](int kc) {
#pragma unroll
    for (int j = 0; j < APT; ++j) {
      int idx = j * 256 + t;
      int row = idx >> 3;   // BK/4 = 8 float4 per row
      int kq = idx & 7;
      int gr = rb + row;
      if (gr >= n) gr = n - 1;  // clamp: load safe, store guarded
      aReg[j] = *(const float4*)&A[(size_t)gr * K + kc + kq * 4];
    }
  };
  auto loadW = [&](int kc) {
#pragma unroll
    for (int j = 0; j < WPT; ++j) {
      int idx = j * 256 + t;
      if ((WTOT % 256 == 0) || idx < WTOT)
        wReg[j] = *(const float4*)&W[(size_t)kc * F + idx * 4];
    }
  };
  auto store = [&]() {
#pragma unroll
    for (int j = 0; j < APT; ++j) {
      int idx = j * 256 + t;
      int row = idx >> 3;
      int kq = idx & 7;
      *(float4*)&As[row * AP + kq * 4] = aReg[j];
    }
#pragma unroll
    for (int j = 0; j < WPT; ++j) {
      int idx = j * 256 + t;
      if ((WTOT % 256 == 0) || idx < WTOT) *(float4*)&Ws[idx * 4] = wReg[j];
    }
  };

  float4 acc[RT];
#pragma unroll
  for (int r = 0; r < RT; ++r) acc[r] = make_float4(0.f, 0.f, 0.f, 0.f);

  loadA(0);
  loadW(0);
  for (int c = 0; c < CHUNKS; ++c) {
    __syncthreads();            // previous chunk's compute done
    store();                    // (implicit vmcnt wait before ds_write)
    __syncthreads();
    if (c + 1 < CHUNKS) {       // prefetch next chunk; latency overlaps FMAs
      loadA((c + 1) * BK);
      loadW((c + 1) * BK);
    }
#pragma unroll
    for (int k4 = 0; k4 < BK / 4; ++k4) {
      float4 w0 = *(const float4*)&Ws[(k4 * 4 + 0) * F + tx * 4];
      float4 w1 = *(const float4*)&Ws[(k4 * 4 + 1) * F + tx * 4];
      float4 w2 = *(const float4*)&Ws[(k4 * 4 + 2) * F + tx * 4];
      float4 w3 = *(const float4*)&Ws[(k4 * 4 + 3) * F + tx * 4];
#pragma unroll
      for (int r = 0; r < RT; ++r) {
        float4 a = *(const float4*)&As[(ty * RT + r) * AP + k4 * 4];
        fmaw(acc[r], a.x, w0);
        fmaw(acc[r], a.y, w1);
        fmaw(acc[r], a.z, w2);
        fmaw(acc[r], a.w, w3);
      }
    }
  }

#pragma unroll
  for (int r = 0; r < RT; ++r) {
    int rr = rb + ty * RT + r;
    if (rr < n) *(float4*)&C[(size_t)rr * F + tx * 4] = acc[r];
  }
}

// ------------------------------ Aggregation --------------------------------
// out[i] = sum_e w_e * h[src_e] + dinv[i]^2 * h[i] + bias   (+ReLU)
template <int F, bool RELU>
__global__ __launch_bounds__(256) void agg_kernel(
    const float* __restrict__ h, const int* __restrict__ row_start,
    const int* __restrict__ cnt, const int2* __restrict__ csr,
    const float* __restrict__ dinv, const float* __restrict__ bias,
    float* __restrict__ out, int n) {
  constexpr int TPN = F / 4;      // lanes per node
  constexpr int NPB = 256 / TPN;  // nodes per block
  int node = blockIdx.x * NPB + threadIdx.x / TPN;
  int lane = threadIdx.x % TPN;
  if (node >= n) return;

  float di = dinv[node];
  float sc = di * di;
  float4 hs = *(const float4*)&h[(size_t)node * F + lane * 4];
  float4 acc = make_float4(hs.x * sc, hs.y * sc, hs.z * sc, hs.w * sc);

  int s = row_start[node];
  int e = s + cnt[node];
  int j = s;
  for (; j + 4 <= e; j += 4) {
    int2 p0 = csr[j];
    int2 p1 = csr[j + 1];
    int2 p2 = csr[j + 2];
    int2 p3 = csr[j + 3];
    float4 g0 = *(const float4*)&h[(size_t)p0.x * F + lane * 4];
    float4 g1 = *(const float4*)&h[(size_t)p1.x * F + lane * 4];
    float4 g2 = *(const float4*)&h[(size_t)p2.x * F + lane * 4];
    float4 g3 = *(const float4*)&h[(size_t)p3.x * F + lane * 4];
    fma4(acc, g0, __int_as_float(p0.y));
    fma4(acc, g1, __int_as_float(p1.y));
    fma4(acc, g2, __int_as_float(p2.y));
    fma4(acc, g3, __int_as_float(p3.y));
  }
  for (; j < e; ++j) {
    int2 p = csr[j];
    float4 g = *(const float4*)&h[(size_t)p.x * F + lane * 4];
    fma4(acc, g, __int_as_float(p.y));
  }

  float4 b4 = *(const float4*)&bias[lane * 4];
  float4 r = make_float4(acc.x + b4.x, acc.y + b4.y, acc.z + b4.z, acc.w + b4.w);
  if (RELU) {
    r.x = fmaxf(r.x, 0.f);
    r.y = fmaxf(r.y, 0.f);
    r.z = fmaxf(r.z, 0.f);
    r.w = fmaxf(r.w, 0.f);
  }
  *(float4*)&out[(size_t)node * F + lane * 4] = r;
}

// -------------------------------- launch -----------------------------------

extern "C" void kernel_launch(void* const* d_in, const int* in_sizes, int n_in,
                              void* d_out, int out_size, void* d_ws, size_t ws_size,
                              hipStream_t stream) {
  const float* x = (const float*)d_in[0];
  const int* edge = (const int*)d_in[1];
  const float* W1 = (const float*)d_in[2];
  const float* b1 = (const float*)d_in[3];
  const float* W2 = (const float*)d_in[4];
  const float* b2 = (const float*)d_in[5];
  const float* W3 = (const float*)d_in[6];
  const float* b3 = (const float*)d_in[7];

  const int N = in_sizes[0] / 128;
  const int E = in_sizes[1] / 2;
  const int* src = edge;       // edge_index[0]
  const int* dstp = edge + E;  // edge_index[1]
  float* out = (float*)d_out;

  size_t off = 0;
  auto take = [&](size_t bytes) -> void* {
    void* r = (char*)d_ws + off;
    off += (bytes + 255) & ~(size_t)255;
    return r;
  };
  int* counter = (int*)take(4);
  int* cnt = (int*)take((size_t)N * 4);
  float* dinv = (float*)take((size_t)N * 4);
  int* row_start = (int*)take((size_t)N * 4);
  int* cursor = (int*)take((size_t)N * 4);
  int2* csr = (int2*)take((size_t)E * 8);
  float* bufh = (float*)take((size_t)N * 128 * 4);
  float* bufa = (float*)take((size_t)N * 128 * 4);

  // zero counter + cnt (first two regions, contiguous)
  hipMemsetAsync(d_ws, 0, 256 + (size_t)N * 4, stream);

  const int TB = 256;
  int eg = (E + TB - 1) / TB;
  int ng = (N + TB - 1) / TB;

  count_kernel<<<eg, TB, 0, stream>>>(dstp, cnt, E);
  alloc_kernel<<<ng, TB, 0, stream>>>(cnt, row_start, cursor, counter, dinv, N);
  scatter_kernel<<<eg, TB, 0, stream>>>(src, dstp, dinv, cursor, csr, E);

  // Layer 1: 128 -> 128 (+ReLU).  RT=8 -> BR=64, grid 782.
  gemm_t<128, 128, 8><<<(N + 63) / 64, 256, 0, stream>>>(x, W1, bufh, N);
  agg_kernel<128, true><<<(N + 7) / 8, 256, 0, stream>>>(bufh, row_start, cnt, csr, dinv, b1,
                                                         bufa, N);
  // Layer 2: 128 -> 64 (+ReLU).  RT=4 -> BR=64, grid 782.
  gemm_t<128, 64, 4><<<(N + 63) / 64, 256, 0, stream>>>(bufa, W2, bufh, N);
  agg_kernel<64, true><<<(N + 15) / 16, 256, 0, stream>>>(bufh, row_start, cnt, csr, dinv, b2,
                                                          bufa, N);
  // Layer 3: 64 -> 16.  RT=1 -> BR=64, grid 782.
  gemm_t<64, 16, 1><<<(N + 63) / 64, 256, 0, stream>>>(bufa, W3, bufh, N);
  agg_kernel<16, false><<<(N + 63) / 64, 256, 0, stream>>>(bufh, row_start, cnt, csr, dinv, b3,
                                                           out, N);
}